// Round 3
// baseline (598.313 us; speedup 1.0000x reference)
//
#include <hip/hip_runtime.h>
#include <math.h>

#define T_LEN 4096
#define C_LEN 256
#define B_LEN 16

// ---------------------------------------------------------------------------
// Compile-time Gaussian kernel bank (matches numpy: exp(-0.5*(j/s)^2), trunc
// at r=int(4*s), normalized by sum+1e-12). Values become instruction literals.
// ---------------------------------------------------------------------------
constexpr double cexp(double x) {
    double y = x * (1.0 / 1024.0);
    double t = 1.0, term = 1.0;
    for (int i = 1; i <= 12; ++i) { term *= y / i; t += term; }
    for (int i = 0; i < 10; ++i) t = t * t;   // ^1024
    return t;
}

constexpr int RAD[5] = {10, 16, 24, 36, 56};

struct Bank { float g[5][57]; };

constexpr Bank make_bank() {
    Bank b{};
    const double sig[5] = {2.5, 4.0, 6.0, 9.0, 14.0};
    for (int k = 0; k < 5; ++k) {
        double w[57] = {};
        for (int j = 0; j <= RAD[k]; ++j)
            w[j] = cexp(-0.5 * (double)(j * j) / (sig[k] * sig[k]));
        double s = w[0];
        for (int j = 1; j <= RAD[k]; ++j) s += 2.0 * w[j];
        s += 1e-12;
        for (int j = 0; j <= RAD[k]; ++j) b.g[k][j] = (float)(w[j] / s);
    }
    return b;
}

constexpr Bank BANK = make_bank();

#define LOG2E 1.4426950408889634f

__device__ __forceinline__ float fast_exp2(float x) {
#if __has_builtin(__builtin_amdgcn_exp2f)
    return __builtin_amdgcn_exp2f(x);
#else
    return __expf(x * 0.6931471805599453f);
#endif
}

// ---------------------------------------------------------------------------
// Transcendental-free GELU.
//   gelu(x) = x*(0.5 + s),  s = 0.5*erf(xa/sqrt2) = xa*P(xa^2),  xa=clamp(x,±4)
// P(t) = (1/sqrt(2pi)) * sum_k (-1)^k (t/2)^k / (k!(2k+1))  -- ENTIRE in t,
// so a degree-12 Chebyshev interpolant on t in [0,16] has err ~1e-5.
// Clamp error: |x|*Phi(-4) <= ~3e-4 per unit for |x|<=10. All coefficients
// are fitted at COMPILE TIME (double precision) below.
// Cost: ~16 full-rate slots vs 21 (5 VALU + exp2/rcp at 1/4 rate) before.
// ---------------------------------------------------------------------------
constexpr int NC = 13;                 // interpolation nodes -> degree 12
constexpr double CPI = 3.14159265358979323846;

constexpr double ccos(double a) {
    while (a > CPI)  a -= 2.0 * CPI;
    while (a < -CPI) a += 2.0 * CPI;
    double t = 1.0, s = 1.0, a2 = a * a;
    for (int k = 1; k <= 25; ++k) { t *= -a2 / ((2.0 * k - 1.0) * (2.0 * k)); s += t; }
    return s;
}

constexpr double Pfun(double t) {      // (1/sqrt(2pi)) * S(t)
    double ht = 0.5 * t;
    double term = 1.0, s = 1.0;        // k=0 term
    for (int k = 1; k <= 60; ++k) {
        term *= ht / k;                // (t/2)^k / k!
        double add = term / (2.0 * k + 1.0);
        s += (k & 1) ? -add : add;
    }
    return s * 0.39894228040143267794; // 1/sqrt(2pi)
}

struct GeluFit { float c[NC]; };

constexpr GeluFit make_fit() {
    double f[NC] = {};
    for (int j = 0; j < NC; ++j) {
        double w = ccos(CPI * (2.0 * j + 1.0) / (2.0 * NC));
        f[j] = Pfun(8.0 + 8.0 * w);    // t = 8 + 8w maps [-1,1] -> [0,16]
    }
    double cheb[NC] = {};
    for (int k = 0; k < NC; ++k) {
        double s = 0.0;
        for (int j = 0; j < NC; ++j)
            s += f[j] * ccos(CPI * k * (2.0 * j + 1.0) / (2.0 * NC));
        cheb[k] = 2.0 * s / NC;
    }
    cheb[0] *= 0.5;
    // Chebyshev -> monomial (in w) via T_{k+1} = 2w T_k - T_{k-1}
    double Tm1[NC] = {}, T0[NC] = {}, mono[NC] = {};
    Tm1[0] = 1.0;  T0[1] = 1.0;
    for (int i = 0; i < NC; ++i) mono[i] = cheb[0] * Tm1[i] + cheb[1] * T0[i];
    for (int k = 2; k < NC; ++k) {
        double Tn[NC] = {};
        for (int i = NC - 1; i >= 1; --i) Tn[i] = 2.0 * T0[i - 1];
        for (int i = 0; i < NC; ++i) Tn[i] -= Tm1[i];
        for (int i = 0; i < NC; ++i) mono[i] += cheb[k] * Tn[i];
        for (int i = 0; i < NC; ++i) { Tm1[i] = T0[i]; T0[i] = Tn[i]; }
    }
    GeluFit g{};
    for (int i = 0; i < NC; ++i) g.c[i] = (float)mono[i];
    return g;
}

constexpr GeluFit GFIT = make_fit();

__device__ __forceinline__ float gelu_fast(float x) {
    float xa = fminf(fmaxf(x, -4.0f), 4.0f);
    float t  = xa * xa;
    float w  = fmaf(t, 0.125f, -1.0f);          // map [0,16] -> [-1,1]
    float p  = GFIT.c[NC - 1];
#pragma unroll
    for (int i = NC - 2; i >= 0; --i) p = fmaf(p, w, GFIT.c[i]);
    float s = xa * p;                           // 0.5*erf(xa/sqrt2)
    return x * (0.5f + s);
}

__device__ __forceinline__ float ldz(const float* __restrict__ xb, int tt) {
    if (tt < 0 || tt >= T_LEN) return 0.0f;
    return xb[tt * C_LEN];
}

// ---------------------------------------------------------------------------
// Per-thread worker: one channel c, 4 consecutive t starting at t0.
// CHECKED=true handles series edges (zero-pad conv, reflect-pad pooling).
// ---------------------------------------------------------------------------
template <bool CHECKED>
__device__ __forceinline__ void work(const float* __restrict__ x,
                                     float* __restrict__ out,
                                     const float (*__restrict__ wle)[8],
                                     const float* __restrict__ w2e,
                                     const float* __restrict__ b2l,
                                     int b, int t0, int c) {
    const float* xb = x + (size_t)b * T_LEN * C_LEN + c;  // index by t*C_LEN

    // ---- pooling window values: x[t0-7 .. t0+11] (reflect at edges) ----
    float v[19];
#pragma unroll
    for (int i = 0; i < 19; ++i) {
        int tt = t0 - 7 + i;
        if (CHECKED) {
            tt = (tt < 0) ? -tt : tt;
            tt = (tt >= T_LEN) ? (2 * T_LEN - 2 - tt) : tt;
        }
        v[i] = xb[tt * C_LEN];
    }

    float mean[4], var[4], xc[4];
    {
        float s = 0.f, q = 0.f;
#pragma unroll
        for (int i = 0; i < 16; ++i) { s += v[i]; q = fmaf(v[i], v[i], q); }
#pragma unroll
        for (int m = 0; m < 4; ++m) {
            if (m > 0) {
                float nw = v[15 + m], od = v[m - 1];
                s = s + nw - od;
                q = fmaf(nw, nw, fmaf(od, -od, q));
            }
            mean[m] = s * 0.0625f;
            float m2 = q * 0.0625f;
            float vv = fmaf(-mean[m], mean[m], m2);
            var[m] = vv > 0.f ? vv : 0.f;
            xc[m]  = v[7 + m];   // x[t0+m] (always in range -> reflect is identity)
        }
    }

    // ---- 5 Gaussian convs, symmetric-pair register sliding windows ----
    float acc[5][4];
#pragma unroll
    for (int k = 0; k < 5; ++k)
#pragma unroll
        for (int m = 0; m < 4; ++m) acc[k][m] = BANK.g[k][0] * xc[m];

    float F[4], Bw[4];
    if (CHECKED) {
        F[1] = ldz(xb, t0 + 1); F[2] = ldz(xb, t0 + 2);
        F[3] = ldz(xb, t0 + 3); F[0] = ldz(xb, t0 + 4);
        Bw[3] = ldz(xb, t0 - 1); Bw[0] = ldz(xb, t0);
        Bw[1] = ldz(xb, t0 + 1); Bw[2] = ldz(xb, t0 + 2);
    } else {
        F[1] = v[8]; F[2] = v[9]; F[3] = v[10]; F[0] = v[11];
        Bw[3] = v[6]; Bw[0] = v[7]; Bw[1] = v[8]; Bw[2] = v[9];
    }

#pragma unroll
    for (int j = 1; j <= 56; ++j) {
        float sm[4];
#pragma unroll
        for (int m = 0; m < 4; ++m)
            sm[m] = F[(j + m) & 3] + Bw[(m - j) & 3];
#pragma unroll
        for (int k = 0; k < 5; ++k) {
            if (j <= RAD[k]) {
#pragma unroll
                for (int m = 0; m < 4; ++m)
                    acc[k][m] = fmaf(BANK.g[k][j], sm[m], acc[k][m]);
            }
        }
        if (j < 56) {
            if (CHECKED) {
                F[j & 3]        = ldz(xb, t0 + j + 4);
                Bw[(3 - j) & 3] = ldz(xb, t0 - j - 1);
            } else {
                F[j & 3]        = (j <= 7) ? v[j + 11] : xb[(t0 + j + 4) * C_LEN];
                Bw[(3 - j) & 3] = (j <= 6) ? v[6 - j]  : xb[(t0 - j - 1) * C_LEN];
            }
        }
    }

    // ---- conditioner MLP: 3 -> 32 (poly GELU) -> 5 logits (pre-scaled by
    // log2e at weight-staging time so softmax uses raw v_exp_f32) ----
    float lg[5][4];
#pragma unroll
    for (int k = 0; k < 5; ++k) {
        float bk = b2l[k];
#pragma unroll
        for (int m = 0; m < 4; ++m) lg[k][m] = bk;
    }

#pragma unroll 2
    for (int i = 0; i < 32; ++i) {
        float4 wa = *(const float4*)&wle[i][0];  // w1_0, w1_1, w1_2, b1
        float4 wb = *(const float4*)&wle[i][4];  // w2_0..w2_3  (x log2e)
        float w24 = w2e[i];                      // w2_4        (x log2e)
#pragma unroll
        for (int m = 0; m < 4; ++m) {
            float pre = fmaf(wa.x, mean[m], fmaf(wa.y, var[m], fmaf(wa.z, xc[m], wa.w)));
            float h = gelu_fast(pre);
            lg[0][m] = fmaf(h, wb.x, lg[0][m]);
            lg[1][m] = fmaf(h, wb.y, lg[1][m]);
            lg[2][m] = fmaf(h, wb.z, lg[2][m]);
            lg[3][m] = fmaf(h, wb.w, lg[3][m]);
            lg[4][m] = fmaf(h, w24 , lg[4][m]);
        }
    }

    // ---- softmax over K=5 (logits already x log2e; bounded, so no max
    // subtraction needed) + mixture, store ----
#pragma unroll
    for (int m = 0; m < 4; ++m) {
        float e0 = fast_exp2(lg[0][m]), e1 = fast_exp2(lg[1][m]);
        float e2 = fast_exp2(lg[2][m]), e3 = fast_exp2(lg[3][m]);
        float e4 = fast_exp2(lg[4][m]);
        float den = ((e0 + e1) + (e2 + e3)) + e4;
        float num = e0 * acc[0][m];
        num = fmaf(e1, acc[1][m], num);
        num = fmaf(e2, acc[2][m], num);
        num = fmaf(e3, acc[3][m], num);
        num = fmaf(e4, acc[4][m], num);
        out[((size_t)b * T_LEN + t0 + m) * C_LEN + c] = num * __builtin_amdgcn_rcpf(den);
    }
}

// ---------------------------------------------------------------------------
// Single fused kernel: boundary chunks (28/1024 per b) take the CHECKED path,
// block-uniform branch.
// ---------------------------------------------------------------------------
__global__ __launch_bounds__(256) void agt_fused(
    const float* __restrict__ x, const float* __restrict__ W1,
    const float* __restrict__ b1, const float* __restrict__ W2,
    const float* __restrict__ b2, float* __restrict__ out) {
    __shared__ __align__(16) float wle[32][8];
    __shared__ float w2e[32];
    __shared__ float b2l[5];
    {
        int tid = threadIdx.x;
        if (tid < 32) {
            wle[tid][0] = W1[tid];
            wle[tid][1] = W1[32 + tid];
            wle[tid][2] = W1[64 + tid];
            wle[tid][3] = b1[tid];
            wle[tid][4] = W2[tid * 5 + 0] * LOG2E;
            wle[tid][5] = W2[tid * 5 + 1] * LOG2E;
            wle[tid][6] = W2[tid * 5 + 2] * LOG2E;
            wle[tid][7] = W2[tid * 5 + 3] * LOG2E;
            w2e[tid]    = W2[tid * 5 + 4] * LOG2E;
            if (tid < 5) b2l[tid] = b2[tid] * LOG2E;
        }
        __syncthreads();
    }
    int b     = blockIdx.x >> 10;        // 1024 chunks per batch
    int chunk = blockIdx.x & 1023;
    int t0    = chunk * 4;
    if (chunk >= 14 && chunk < 1010)
        work<false>(x, out, wle, w2e, b2l, b, t0, threadIdx.x);
    else
        work<true>(x, out, wle, w2e, b2l, b, t0, threadIdx.x);
}

extern "C" void kernel_launch(void* const* d_in, const int* in_sizes, int n_in,
                              void* d_out, int out_size, void* d_ws, size_t ws_size,
                              hipStream_t stream) {
    const float* x  = (const float*)d_in[0];
    const float* W1 = (const float*)d_in[1];
    const float* b1 = (const float*)d_in[2];
    const float* W2 = (const float*)d_in[3];
    const float* b2 = (const float*)d_in[4];
    float* out = (float*)d_out;

    (void)in_sizes; (void)n_in; (void)d_ws; (void)ws_size; (void)out_size;

    agt_fused<<<dim3(B_LEN * 1024), dim3(256), 0, stream>>>(x, W1, b1, W2, b2, out);
}